// Round 18
// baseline (185.028 us; speedup 1.0000x reference)
//
#include <hip/hip_runtime.h>
#include <math.h>

// Problem constants (from reference)
#define BB   8      // batch
#define MM   4      // MAXM
#define DD   128    // DIM
#define NHH  8      // heads
#define QDD  16     // head dim
#define NN   256    // H*W
#define KO   128    // NH*QD
#define ATILE 16    // i-rows per a_kernel block
#define DTILE 8     // D-rows per out_kernel block

typedef float v2f __attribute__((ext_vector_type(2)));
#define PKFMA(a, b, c) __builtin_elementwise_fma((a), (b), (c))

// ---------------------------------------------------------------------------
// Kernel 0 (trig-free): pe[m,i,j] = exp(i*m*theta) = ((dx+i*dy)/r)^m.
// ---------------------------------------------------------------------------
__global__ void pe_kernel(float2* __restrict__ peIJ, float2* __restrict__ peT) {
    int bid = blockIdx.x;           // m*N + i
    int m = bid >> 8;
    int i = bid & 255;
    int j = threadIdx.x;
    float dy = (float)((j >> 4) - (i >> 4));
    float dx = (float)((j & 15) - (i & 15));
    float r2 = dx * dx + dy * dy;
    float c1 = 1.f, s1 = 0.f;
    if (r2 > 0.f) {
        float rinv = rsqrtf(r2);
        c1 = dx * rinv; s1 = dy * rinv;
    }
    float c = 1.f, s = 0.f;
    for (int k = 0; k < m; ++k) {   // m is block-uniform (0..3)
        float nc = c * c1 - s * s1;
        s = c * s1 + s * c1;
        c = nc;
    }
    peIJ[(m * NN + i) * NN + j] = make_float2(c, s);
    peT[(m * NN + j) * NN + i] = make_float2(c, s);
}

// ---------------------------------------------------------------------------
// Kernel 1 (v9 = v8 + packed fp32): E[t,b,m,h,q,n] = sum_D emb*x.
// Inner complex FMAs packed over n-pairs via v2f + elementwise_fma ->
// v_pk_fma_f32 (VOP3P), halving VALU instruction count (issue-bound theory).
// ---------------------------------------------------------------------------
__global__ __launch_bounds__(256, 3)
void e_kernel(const float* __restrict__ xr, const float* __restrict__ xi,
              const float* __restrict__ er, const float* __restrict__ ei,
              float2* __restrict__ E) {
    int bid = blockIdx.x;
    int xcd = bid & 7;
    int idx = bid >> 3;                   // 0..95
    int pair = xcd * 4 + (idx & 3);       // b*MM+m, 0..31
    int th  = idx >> 2;                   // 0..23 = t*NHH+h
    int t = th >> 3;
    int h = th & 7;
    int b = pair >> 2;
    int m = pair & 3;
    int tid = threadIdx.x;
    int wav = tid >> 6;                   // 0..3 (wave id = q-quad)
    int lane = tid & 63;                  // n = 4*lane .. 4*lane+3

    __shared__ float2 semb[QDD * DD];     // 16 KB, [q*128+D] (linear)
    int base = (((t * MM + m) * NHH + h) * QDD) * DD;
    for (int i2 = tid; i2 < QDD * DD; i2 += 256)
        semb[i2] = make_float2(er[base + i2], ei[base + i2]);
    __syncthreads();

    v2f accr[4][2], acci[4][2];           // [qq][n-half]
#pragma unroll
    for (int q = 0; q < 4; ++q)
#pragma unroll
        for (int hh = 0; hh < 2; ++hh) { accr[q][hh] = (v2f)(0.f); acci[q][hh] = (v2f)(0.f); }

    const float4* xr4 = (const float4*)(xr + (size_t)((b * MM + m) * DD) * NN);
    const float4* xi4 = (const float4*)(xi + (size_t)((b * MM + m) * DD) * NN);
    const float2* sq = semb + wav * 4 * DD;   // this wave's 4 q rows

    for (int Dc = 0; Dc < DD; Dc += 4) {
        float2 em[4][4];
#pragma unroll
        for (int qq = 0; qq < 4; ++qq)
#pragma unroll
            for (int d = 0; d < 4; ++d)
                em[qq][d] = sq[qq * DD + Dc + d];
        float4 vr[4], vi[4];
#pragma unroll
        for (int d = 0; d < 4; ++d) {
            vr[d] = xr4[(Dc + d) * 64 + lane];
            vi[d] = xi4[(Dc + d) * 64 + lane];
        }
#pragma unroll
        for (int d = 0; d < 4; ++d) {
            v2f vr0 = {vr[d].x, vr[d].y}, vr1 = {vr[d].z, vr[d].w};
            v2f vi0 = {vi[d].x, vi[d].y}, vi1 = {vi[d].z, vi[d].w};
#pragma unroll
            for (int qq = 0; qq < 4; ++qq) {
                float2 e = em[qq][d];
                v2f ex  = {e.x, e.x};
                v2f ey  = {e.y, e.y};
                v2f ney = -ey;
                accr[qq][0] = PKFMA(ex, vr0, PKFMA(ney, vi0, accr[qq][0]));
                acci[qq][0] = PKFMA(ex, vi0, PKFMA(ey,  vr0, acci[qq][0]));
                accr[qq][1] = PKFMA(ex, vr1, PKFMA(ney, vi1, accr[qq][1]));
                acci[qq][1] = PKFMA(ex, vi1, PKFMA(ey,  vr1, acci[qq][1]));
            }
        }
    }

    size_t ebase = (size_t)((((t * BB + b) * MM + m) * NHH + h) * QDD + wav * 4) * NN
                 + 4 * lane;
#pragma unroll
    for (int qq = 0; qq < 4; ++qq) {
        float4* E4 = (float4*)(E + ebase + (size_t)qq * NN);
        E4[0] = make_float4(accr[qq][0].x, acci[qq][0].x, accr[qq][0].y, acci[qq][0].y);
        E4[1] = make_float4(accr[qq][1].x, acci[qq][1].x, accr[qq][1].y, acci[qq][1].y);
    }
}

// ---------------------------------------------------------------------------
// Kernel 2: QE[b,m,h,i] = sum_q conj(E0[b,m,h,q,i]) * enc0[m,h,q]
// ---------------------------------------------------------------------------
__global__ void qe_kernel(const float2* __restrict__ E,
                          const float* __restrict__ encr, const float* __restrict__ enci,
                          float2* __restrict__ QE) {
    int bid = blockIdx.x;                 // (b*MM+m)*NHH + h
    int i = threadIdx.x;
    const float2* e0 = E + (size_t)(bid) * QDD * NN;   // t=0 plane
    int h = bid & 7;
    int bm = bid >> 3;
    int m = bm & 3;
    int encbase = (m * NHH + h) * QDD;    // enc[0,m,h,0,q,0]
    float ar = 0.f, ai = 0.f;
#pragma unroll
    for (int q = 0; q < QDD; ++q) {
        float2 e = e0[q * NN + i];
        float cr = encr[encbase + q], ci = enci[encbase + q];
        // conj(e) * enc
        ar = fmaf(e.x, cr, fmaf( e.y, ci, ar));
        ai = fmaf(e.x, ci, fmaf(-e.y, cr, ai));
    }
    QE[(size_t)bid * NN + i] = make_float2(ar, ai);
}

// ---------------------------------------------------------------------------
// Kernel 3 (v3 = register-tiled + XCD swizzle + packed fp32): A[b,h,i,j].
// e0/QE staged as SoA (seX/seY) so r-pairs are v2f; main loop FMAs packed
// over r (v_pk_fma_f32), halving VALU instruction count. kreg splats hoisted
// per q; LDS v2f reads are block-uniform -> broadcast, conflict-free.
// ---------------------------------------------------------------------------
__global__ void a_kernel(const float2* __restrict__ E, const float2* __restrict__ QE,
                         const float2* __restrict__ peIJ, float2* __restrict__ A) {
    int bid = blockIdx.x;
    int xcd = bid & 7;
    int idx = bid >> 3;                   // 0..127
    int bh = xcd * 8 + (idx & 7);         // b*NHH+h, 0..63
    int itile = idx >> 3;                 // 0..15
    int h = bh & 7;
    int b = bh >> 3;
    int j = threadIdx.x;
    int i0 = itile * ATILE;

    __shared__ float2 sk[QDD][NN];        // 32 KB
    __shared__ v2f seX2[QDD][ATILE / 2];  // 1 KB, e0.x SoA (r-pairs)
    __shared__ v2f seY2[QDD][ATILE / 2];  // 1 KB, e0.y SoA
    __shared__ v2f sqeX2[ATILE / 2];
    __shared__ v2f sqeY2[ATILE / 2];

    v2f ar2[8], ai2[8];
#pragma unroll
    for (int rp = 0; rp < 8; ++rp) { ar2[rp] = (v2f)(0.f); ai2[rp] = (v2f)(0.f); }

    for (int m = 0; m < MM; ++m) {
        const float2* kk = E + (size_t)((((BB + b) * MM + m) * NHH + h) * QDD) * NN; // t=1
        const float2* e0 = E + (size_t)(((b * MM + m) * NHH + h) * QDD) * NN;        // t=0
        __syncthreads();
        for (int i2 = threadIdx.x; i2 < QDD * NN; i2 += 256)
            sk[i2 >> 8][i2 & 255] = kk[i2];
        {
            int q = threadIdx.x & 15;
            int r = threadIdx.x >> 4;     // 0..15
            float2 e = e0[q * NN + i0 + r];
            ((float*)seX2)[q * ATILE + r] = e.x;
            ((float*)seY2)[q * ATILE + r] = e.y;
        }
        if (threadIdx.x < ATILE) {
            float2 qe = QE[(size_t)((b * MM + m) * NHH + h) * NN + i0 + threadIdx.x];
            ((float*)sqeX2)[threadIdx.x] = qe.x;
            ((float*)sqeY2)[threadIdx.x] = qe.y;
        }
        __syncthreads();

        // this thread's K column into registers
        float2 kreg[QDD];
#pragma unroll
        for (int q = 0; q < QDD; ++q) kreg[q] = sk[q][j];

#pragma unroll
        for (int q = 0; q < QDD; ++q) {
            v2f kx  = {kreg[q].x, kreg[q].x};
            v2f ky  = {kreg[q].y, kreg[q].y};
            v2f nkx = -kx;
#pragma unroll
            for (int rp = 0; rp < 8; ++rp) {
                v2f ex = seX2[q][rp];     // block-uniform broadcast
                v2f ey = seY2[q][rp];
                // ar[r] += e.x*k.x + e.y*k.y ; ai[r] += e.x*k.y - e.y*k.x
                ar2[rp] = PKFMA(ex, kx, PKFMA(ey, ky,  ar2[rp]));
                ai2[rp] = PKFMA(ex, ky, PKFMA(ey, nkx, ai2[rp]));
            }
        }

        // pe term: ar[r] += qe.x*p.x - qe.y*p.y ; ai[r] += qe.x*p.y + qe.y*p.x
#pragma unroll
        for (int rp = 0; rp < 8; ++rp) {
            float2 p0 = peIJ[(size_t)(m * NN + i0 + 2 * rp) * NN + j];     // coalesced
            float2 p1 = peIJ[(size_t)(m * NN + i0 + 2 * rp + 1) * NN + j];
            v2f px = {p0.x, p1.x}, py = {p0.y, p1.y};
            v2f qx = sqeX2[rp], qy = sqeY2[rp];
            v2f nqy = -qy;
            ar2[rp] = PKFMA(px, qx, PKFMA(py, nqy, ar2[rp]));
            ai2[rp] = PKFMA(py, qx, PKFMA(px, qy,  ai2[rp]));
        }
    }
#pragma unroll
    for (int rp = 0; rp < 8; ++rp) {
        A[(size_t)(bh * NN + i0 + 2 * rp) * NN + j]     = make_float2(ar2[rp].x, ai2[rp].x);
        A[(size_t)(bh * NN + i0 + 2 * rp + 1) * NN + j] = make_float2(ar2[rp].y, ai2[rp].y);
    }
}

// ---------------------------------------------------------------------------
// Kernel 4: row softmax of |A|/4 over j; writes TRANSPOSED Aw:
//   AwT[(bh*N + j)*N + i]
// ---------------------------------------------------------------------------
__global__ void softmax_kernel(const float2* __restrict__ A, float* __restrict__ AwT) {
    int row = blockIdx.x;                 // (b*NHH+h)*NN + i
    int j = threadIdx.x;
    float2 a = A[(size_t)row * NN + j];
    float v = sqrtf(fmaf(a.x, a.x, a.y * a.y)) * 0.25f;

    __shared__ float smax[4];
    __shared__ float ssum[4];
    int lane = threadIdx.x & 63;
    int wid  = threadIdx.x >> 6;

    float mv = v;
#pragma unroll
    for (int off = 32; off > 0; off >>= 1) mv = fmaxf(mv, __shfl_xor(mv, off));
    if (lane == 0) smax[wid] = mv;
    __syncthreads();
    float mx = fmaxf(fmaxf(smax[0], smax[1]), fmaxf(smax[2], smax[3]));

    float e = expf(v - mx);
    float sv = e;
#pragma unroll
    for (int off = 32; off > 0; off >>= 1) sv += __shfl_xor(sv, off);
    if (lane == 0) ssum[wid] = sv;
    __syncthreads();
    float sum = ssum[0] + ssum[1] + ssum[2] + ssum[3];

    float aw = e / sum;
    int bh = row >> 8;
    int i  = row & 255;
    AwT[(size_t)(bh * NN + j) * NN + i] = aw;
}

// ---------------------------------------------------------------------------
// Kernel 5 (qh-split + XCD swizzle): 512 blocks = 64 idx x 8 xcd.
// ---------------------------------------------------------------------------
__global__ __launch_bounds__(512)
void res_kernel(const float2* __restrict__ E, const float* __restrict__ AwT,
                const float2* __restrict__ peT,
                const float* __restrict__ encr, const float* __restrict__ enci,
                float2* __restrict__ Res) {
    int bid = blockIdx.x;
    int xcd = bid & 7;
    int idx = bid >> 3;                   // 0..63
    int bh = xcd * 8 + (idx & 7);         // b*NHH+h
    int mqh = idx >> 3;                   // 0..7
    int m  = mqh >> 1;
    int qh = mqh & 1;
    int h = bh & 7;
    int b = bh >> 3;
    int i = threadIdx.x & 255;
    int g = threadIdx.x >> 8;             // j-half 0/1

    __shared__ float2 sv[8][NN];          // 16 KB: this qh's 8 V rows
    __shared__ float2 spA[NN][9];         // 18 KB: g=1 partials (8 acc + PA)
    __shared__ float2 senc[8];

    const float2* V = E + ((size_t)(((2 * BB + b) * MM + m) * NHH + h) * QDD + qh * 8) * NN;
    for (int i2 = threadIdx.x; i2 < 8 * NN; i2 += 512) sv[i2 >> 8][i2 & 255] = V[i2];
    if (threadIdx.x < 8) {
        int eb = ((MM + m) * NHH + h) * QDD + qh * 8 + threadIdx.x;   // enc[1,...]
        senc[threadIdx.x] = make_float2(encr[eb], enci[eb]);
    }
    __syncthreads();

    float accr[8], acci[8];
#pragma unroll
    for (int q = 0; q < 8; ++q) { accr[q] = 0.f; acci[q] = 0.f; }
    float par = 0.f, pai = 0.f;

    const float*  awp = AwT + (size_t)((b * NHH + h) * NN) * NN + i;
    const float2* pep = peT + (size_t)(m * NN) * NN + i;
    int j0 = g * (NN / 2);
    for (int j = j0; j < j0 + NN / 2; ++j) {
        float aw  = awp[(size_t)j * NN];      // coalesced over i
        float2 p  = pep[(size_t)j * NN];      // coalesced over i
        par = fmaf(p.x, aw, par);
        pai = fmaf(p.y, aw, pai);
#pragma unroll
        for (int q = 0; q < 8; ++q) {
            float2 vv = sv[q][j];             // wave-uniform -> broadcast
            accr[q] = fmaf(vv.x, aw, accr[q]);
            acci[q] = fmaf(vv.y, aw, acci[q]);
        }
    }

    if (g == 1) {
#pragma unroll
        for (int q = 0; q < 8; ++q) spA[i][q] = make_float2(accr[q], acci[q]);
        spA[i][8] = make_float2(par, pai);
    }
    __syncthreads();
    if (g == 0) {
#pragma unroll
        for (int q = 0; q < 8; ++q) {
            float2 o = spA[i][q];
            accr[q] += o.x; acci[q] += o.y;
        }
        float2 o = spA[i][8];
        par += o.x; pai += o.y;

        float2* rp = Res + ((size_t)((b * MM + m) * KO + h * QDD + qh * 8)) * NN + i;
#pragma unroll
        for (int q = 0; q < 8; ++q) {
            float2 e1 = senc[q];
            float rr = accr[q] + e1.x * par - e1.y * pai;
            float ri = acci[q] + e1.x * pai + e1.y * par;
            rp[(size_t)q * NN] = make_float2(rr, ri);
        }
    }
}

// ---------------------------------------------------------------------------
// Kernel 6 (DTILE=8 + XCD swizzle): out[b,m,D,n] = sum_k w_out*res.
// ---------------------------------------------------------------------------
__global__ void out_kernel(const float2* __restrict__ Res,
                           const float* __restrict__ wor, const float* __restrict__ woi,
                           float* __restrict__ out) {
    int bid = blockIdx.x;
    int xcd = bid & 7;
    int idx = bid >> 3;                   // 0..63
    int bm = xcd * 4 + (idx & 3);         // b*MM+m, 0..31
    int dt = idx >> 2;                    // 0..15
    int n = threadIdx.x;
    int D0 = dt * DTILE;
    int m = bm & 3;

    __shared__ float2 sw[DTILE][KO];      // 8 KB
    for (int i2 = threadIdx.x; i2 < DTILE * KO; i2 += 256) {
        int d = i2 >> 7, k = i2 & 127;
        int wb = (m * DD + D0 + d) * KO + k;
        sw[d][k] = make_float2(wor[wb], woi[wb]);
    }
    __syncthreads();

    const float2* rp = Res + (size_t)(bm * KO) * NN + n;
    float ar[DTILE], ai[DTILE];
#pragma unroll
    for (int d = 0; d < DTILE; ++d) { ar[d] = 0.f; ai[d] = 0.f; }

    for (int k = 0; k < KO; ++k) {
        float2 r = rp[(size_t)k * NN];    // coalesced
#pragma unroll
        for (int d = 0; d < DTILE; ++d) {
            float2 w = sw[d][k];          // broadcast
            ar[d] = fmaf(w.x, r.x, fmaf(-w.y, r.y, ar[d]));
            ai[d] = fmaf(w.x, r.y, fmaf( w.y, r.x, ai[d]));
        }
    }
#pragma unroll
    for (int d = 0; d < DTILE; ++d) {
        size_t ob = (size_t)(bm * DD + D0 + d) * NN + n;
        out[ob] = ar[d];
        out[(size_t)BB * MM * DD * NN + ob] = ai[d];
    }
}

// ---------------------------------------------------------------------------
extern "C" void kernel_launch(void* const* d_in, const int* in_sizes, int n_in,
                              void* d_out, int out_size, void* d_ws, size_t ws_size,
                              hipStream_t stream) {
    (void)in_sizes; (void)n_in; (void)out_size; (void)ws_size;

    const float* x_re   = (const float*)d_in[0];
    const float* x_im   = (const float*)d_in[1];
    const float* emb_re = (const float*)d_in[2];
    const float* emb_im = (const float*)d_in[3];
    const float* enc_re = (const float*)d_in[4];
    const float* enc_im = (const float*)d_in[5];
    const float* out_re = (const float*)d_in[6];
    const float* out_im = (const float*)d_in[7];
    float* out = (float*)d_out;

    // Workspace layout (floats). Total ~155.7 MB.
    float* ws = (float*)d_ws;
    size_t off = 0;
    float2* peIJ = (float2*)(ws + off); off += (size_t)MM * NN * NN * 2;          // 524288
    float2* peT  = (float2*)(ws + off); off += (size_t)MM * NN * NN * 2;          // 524288
    float2* E    = (float2*)(ws + off); off += (size_t)3 * BB * MM * NHH * QDD * NN * 2; // 25165824
    float2* QE   = (float2*)(ws + off); off += (size_t)BB * MM * NHH * NN * 2;    // 131072
    float2* A    = (float2*)(ws + off); off += (size_t)BB * NHH * NN * NN * 2;    // 8388608
    float*  AwT  = (float*)(ws + off);  off += (size_t)BB * NHH * NN * NN;        // 4194304
    float2* Res  = A;  // alias: A is dead after softmax; Res needs 2097152 floats

    pe_kernel<<<MM * NN, 256, 0, stream>>>(peIJ, peT);
    e_kernel<<<3 * BB * MM * NHH, 256, 0, stream>>>(x_re, x_im, emb_re, emb_im, E);
    qe_kernel<<<BB * MM * NHH, 256, 0, stream>>>(E, enc_re, enc_im, QE);
    a_kernel<<<BB * NHH * ATILE, 256, 0, stream>>>(E, QE, peIJ, A);
    softmax_kernel<<<BB * NHH * NN, 256, 0, stream>>>(A, AwT);
    res_kernel<<<BB * MM * NHH * 2, 512, 0, stream>>>(E, AwT, peT, enc_re, enc_im, Res);
    out_kernel<<<BB * MM * (DD / DTILE), 256, 0, stream>>>(Res, out_re, out_im, out);
}

// Round 19
// 180.997 us; speedup vs baseline: 1.0223x; 1.0223x over previous
//
#include <hip/hip_runtime.h>
#include <math.h>

// Problem constants (from reference)
#define BB   8      // batch
#define MM   4      // MAXM
#define DD   128    // DIM
#define NHH  8      // heads
#define QDD  16     // head dim
#define NN   256    // H*W
#define KO   128    // NH*QD
#define ATILE 16    // i-rows per a_kernel block
#define DTILE 8     // D-rows per out_kernel block

typedef float v2f __attribute__((ext_vector_type(2)));
#define PKFMA(a, b, c) __builtin_elementwise_fma((a), (b), (c))

// ---------------------------------------------------------------------------
// Kernel 0 (trig-free): pe[m,i,j] = exp(i*m*theta) = ((dx+i*dy)/r)^m.
// ---------------------------------------------------------------------------
__global__ void pe_kernel(float2* __restrict__ peIJ, float2* __restrict__ peT) {
    int bid = blockIdx.x;           // m*N + i
    int m = bid >> 8;
    int i = bid & 255;
    int j = threadIdx.x;
    float dy = (float)((j >> 4) - (i >> 4));
    float dx = (float)((j & 15) - (i & 15));
    float r2 = dx * dx + dy * dy;
    float c1 = 1.f, s1 = 0.f;
    if (r2 > 0.f) {
        float rinv = rsqrtf(r2);
        c1 = dx * rinv; s1 = dy * rinv;
    }
    float c = 1.f, s = 0.f;
    for (int k = 0; k < m; ++k) {   // m is block-uniform (0..3)
        float nc = c * c1 - s * s1;
        s = c * s1 + s * c1;
        c = nc;
    }
    peIJ[(m * NN + i) * NN + j] = make_float2(c, s);
    peT[(m * NN + j) * NN + i] = make_float2(c, s);
}

// ---------------------------------------------------------------------------
// Kernel 1 (v10 = v9 + cooperative x staging): E[t,b,m,h,q,n] = sum_D emb*x.
// KEY FIX: v9's 4 waves each loaded the identical 256KB x-slice from global
// (4x redundant L2 traffic = 768MB kernel-wide). Now each 8-row D-chunk is
// staged in LDS ONCE per block and consumed by all 4 waves.
// ---------------------------------------------------------------------------
__global__ __launch_bounds__(256, 3)
void e_kernel(const float* __restrict__ xr, const float* __restrict__ xi,
              const float* __restrict__ er, const float* __restrict__ ei,
              float2* __restrict__ E) {
    int bid = blockIdx.x;
    int xcd = bid & 7;
    int idx = bid >> 3;                   // 0..95
    int pair = xcd * 4 + (idx & 3);       // b*MM+m, 0..31
    int th  = idx >> 2;                   // 0..23 = t*NHH+h
    int t = th >> 3;
    int h = th & 7;
    int b = pair >> 2;
    int m = pair & 3;
    int tid = threadIdx.x;
    int wav = tid >> 6;                   // 0..3 (wave id = q-quad)
    int lane = tid & 63;                  // n = 4*lane .. 4*lane+3

    __shared__ float2 semb[QDD * DD];     // 16 KB, [q*128+D] (linear)
    __shared__ float4 sxr4[8 * 64];       // 8 KB: x_re chunk (8 D-rows)
    __shared__ float4 sxi4[8 * 64];       // 8 KB: x_im chunk
    int base = (((t * MM + m) * NHH + h) * QDD) * DD;
    for (int i2 = tid; i2 < QDD * DD; i2 += 256)
        semb[i2] = make_float2(er[base + i2], ei[base + i2]);

    v2f accr[4][2], acci[4][2];           // [qq][n-half]
#pragma unroll
    for (int q = 0; q < 4; ++q)
#pragma unroll
        for (int hh = 0; hh < 2; ++hh) { accr[q][hh] = (v2f)(0.f); acci[q][hh] = (v2f)(0.f); }

    const float4* xr4 = (const float4*)(xr + (size_t)((b * MM + m) * DD) * NN);
    const float4* xi4 = (const float4*)(xi + (size_t)((b * MM + m) * DD) * NN);
    const float2* sq = semb + wav * 4 * DD;   // this wave's 4 q rows

    for (int Dc = 0; Dc < DD; Dc += 8) {
        __syncthreads();                  // protect previous chunk (also covers semb)
        // stage 8 contiguous D-rows: 512 float4 re + 512 float4 im, coalesced
        const float4* srcR = xr4 + Dc * 64;
        const float4* srcI = xi4 + Dc * 64;
        sxr4[tid]       = srcR[tid];
        sxr4[tid + 256] = srcR[tid + 256];
        sxi4[tid]       = srcI[tid];
        sxi4[tid + 256] = srcI[tid + 256];
        __syncthreads();

#pragma unroll
        for (int d = 0; d < 8; ++d) {
            float4 vr = sxr4[d * 64 + lane];   // b128, conflict-free
            float4 vi = sxi4[d * 64 + lane];
            v2f vr0 = {vr.x, vr.y}, vr1 = {vr.z, vr.w};
            v2f vi0 = {vi.x, vi.y}, vi1 = {vi.z, vi.w};
#pragma unroll
            for (int qq = 0; qq < 4; ++qq) {
                float2 e = sq[qq * DD + Dc + d];  // wave-uniform broadcast
                v2f ex  = {e.x, e.x};
                v2f ey  = {e.y, e.y};
                v2f ney = -ey;
                accr[qq][0] = PKFMA(ex, vr0, PKFMA(ney, vi0, accr[qq][0]));
                acci[qq][0] = PKFMA(ex, vi0, PKFMA(ey,  vr0, acci[qq][0]));
                accr[qq][1] = PKFMA(ex, vr1, PKFMA(ney, vi1, accr[qq][1]));
                acci[qq][1] = PKFMA(ex, vi1, PKFMA(ey,  vr1, acci[qq][1]));
            }
        }
    }

    size_t ebase = (size_t)((((t * BB + b) * MM + m) * NHH + h) * QDD + wav * 4) * NN
                 + 4 * lane;
#pragma unroll
    for (int qq = 0; qq < 4; ++qq) {
        float4* E4 = (float4*)(E + ebase + (size_t)qq * NN);
        E4[0] = make_float4(accr[qq][0].x, acci[qq][0].x, accr[qq][0].y, acci[qq][0].y);
        E4[1] = make_float4(accr[qq][1].x, acci[qq][1].x, accr[qq][1].y, acci[qq][1].y);
    }
}

// ---------------------------------------------------------------------------
// Kernel 2: QE[b,m,h,i] = sum_q conj(E0[b,m,h,q,i]) * enc0[m,h,q]
// ---------------------------------------------------------------------------
__global__ void qe_kernel(const float2* __restrict__ E,
                          const float* __restrict__ encr, const float* __restrict__ enci,
                          float2* __restrict__ QE) {
    int bid = blockIdx.x;                 // (b*MM+m)*NHH + h
    int i = threadIdx.x;
    const float2* e0 = E + (size_t)(bid) * QDD * NN;   // t=0 plane
    int h = bid & 7;
    int bm = bid >> 3;
    int m = bm & 3;
    int encbase = (m * NHH + h) * QDD;    // enc[0,m,h,0,q,0]
    float ar = 0.f, ai = 0.f;
#pragma unroll
    for (int q = 0; q < QDD; ++q) {
        float2 e = e0[q * NN + i];
        float cr = encr[encbase + q], ci = enci[encbase + q];
        // conj(e) * enc
        ar = fmaf(e.x, cr, fmaf( e.y, ci, ar));
        ai = fmaf(e.x, ci, fmaf(-e.y, cr, ai));
    }
    QE[(size_t)bid * NN + i] = make_float2(ar, ai);
}

// ---------------------------------------------------------------------------
// Kernel 3 (register-tiled + XCD swizzle + packed fp32): A[b,h,i,j].
// ---------------------------------------------------------------------------
__global__ void a_kernel(const float2* __restrict__ E, const float2* __restrict__ QE,
                         const float2* __restrict__ peIJ, float2* __restrict__ A) {
    int bid = blockIdx.x;
    int xcd = bid & 7;
    int idx = bid >> 3;                   // 0..127
    int bh = xcd * 8 + (idx & 7);         // b*NHH+h, 0..63
    int itile = idx >> 3;                 // 0..15
    int h = bh & 7;
    int b = bh >> 3;
    int j = threadIdx.x;
    int i0 = itile * ATILE;

    __shared__ float2 sk[QDD][NN];        // 32 KB
    __shared__ v2f seX2[QDD][ATILE / 2];  // 1 KB, e0.x SoA (r-pairs)
    __shared__ v2f seY2[QDD][ATILE / 2];  // 1 KB, e0.y SoA
    __shared__ v2f sqeX2[ATILE / 2];
    __shared__ v2f sqeY2[ATILE / 2];

    v2f ar2[8], ai2[8];
#pragma unroll
    for (int rp = 0; rp < 8; ++rp) { ar2[rp] = (v2f)(0.f); ai2[rp] = (v2f)(0.f); }

    for (int m = 0; m < MM; ++m) {
        const float2* kk = E + (size_t)((((BB + b) * MM + m) * NHH + h) * QDD) * NN; // t=1
        const float2* e0 = E + (size_t)(((b * MM + m) * NHH + h) * QDD) * NN;        // t=0
        __syncthreads();
        for (int i2 = threadIdx.x; i2 < QDD * NN; i2 += 256)
            sk[i2 >> 8][i2 & 255] = kk[i2];
        {
            int q = threadIdx.x & 15;
            int r = threadIdx.x >> 4;     // 0..15
            float2 e = e0[q * NN + i0 + r];
            ((float*)seX2)[q * ATILE + r] = e.x;
            ((float*)seY2)[q * ATILE + r] = e.y;
        }
        if (threadIdx.x < ATILE) {
            float2 qe = QE[(size_t)((b * MM + m) * NHH + h) * NN + i0 + threadIdx.x];
            ((float*)sqeX2)[threadIdx.x] = qe.x;
            ((float*)sqeY2)[threadIdx.x] = qe.y;
        }
        __syncthreads();

        // this thread's K column into registers
        float2 kreg[QDD];
#pragma unroll
        for (int q = 0; q < QDD; ++q) kreg[q] = sk[q][j];

#pragma unroll
        for (int q = 0; q < QDD; ++q) {
            v2f kx  = {kreg[q].x, kreg[q].x};
            v2f ky  = {kreg[q].y, kreg[q].y};
            v2f nkx = -kx;
#pragma unroll
            for (int rp = 0; rp < 8; ++rp) {
                v2f ex = seX2[q][rp];     // block-uniform broadcast
                v2f ey = seY2[q][rp];
                // ar[r] += e.x*k.x + e.y*k.y ; ai[r] += e.x*k.y - e.y*k.x
                ar2[rp] = PKFMA(ex, kx, PKFMA(ey, ky,  ar2[rp]));
                ai2[rp] = PKFMA(ex, ky, PKFMA(ey, nkx, ai2[rp]));
            }
        }

        // pe term: ar[r] += qe.x*p.x - qe.y*p.y ; ai[r] += qe.x*p.y + qe.y*p.x
#pragma unroll
        for (int rp = 0; rp < 8; ++rp) {
            float2 p0 = peIJ[(size_t)(m * NN + i0 + 2 * rp) * NN + j];     // coalesced
            float2 p1 = peIJ[(size_t)(m * NN + i0 + 2 * rp + 1) * NN + j];
            v2f px = {p0.x, p1.x}, py = {p0.y, p1.y};
            v2f qx = sqeX2[rp], qy = sqeY2[rp];
            v2f nqy = -qy;
            ar2[rp] = PKFMA(px, qx, PKFMA(py, nqy, ar2[rp]));
            ai2[rp] = PKFMA(py, qx, PKFMA(px, qy,  ai2[rp]));
        }
    }
#pragma unroll
    for (int rp = 0; rp < 8; ++rp) {
        A[(size_t)(bh * NN + i0 + 2 * rp) * NN + j]     = make_float2(ar2[rp].x, ai2[rp].x);
        A[(size_t)(bh * NN + i0 + 2 * rp + 1) * NN + j] = make_float2(ar2[rp].y, ai2[rp].y);
    }
}

// ---------------------------------------------------------------------------
// Kernel 4: row softmax of |A|/4 over j; writes TRANSPOSED Aw:
//   AwT[(bh*N + j)*N + i]
// ---------------------------------------------------------------------------
__global__ void softmax_kernel(const float2* __restrict__ A, float* __restrict__ AwT) {
    int row = blockIdx.x;                 // (b*NHH+h)*NN + i
    int j = threadIdx.x;
    float2 a = A[(size_t)row * NN + j];
    float v = sqrtf(fmaf(a.x, a.x, a.y * a.y)) * 0.25f;

    __shared__ float smax[4];
    __shared__ float ssum[4];
    int lane = threadIdx.x & 63;
    int wid  = threadIdx.x >> 6;

    float mv = v;
#pragma unroll
    for (int off = 32; off > 0; off >>= 1) mv = fmaxf(mv, __shfl_xor(mv, off));
    if (lane == 0) smax[wid] = mv;
    __syncthreads();
    float mx = fmaxf(fmaxf(smax[0], smax[1]), fmaxf(smax[2], smax[3]));

    float e = expf(v - mx);
    float sv = e;
#pragma unroll
    for (int off = 32; off > 0; off >>= 1) sv += __shfl_xor(sv, off);
    if (lane == 0) ssum[wid] = sv;
    __syncthreads();
    float sum = ssum[0] + ssum[1] + ssum[2] + ssum[3];

    float aw = e / sum;
    int bh = row >> 8;
    int i  = row & 255;
    AwT[(size_t)(bh * NN + j) * NN + i] = aw;
}

// ---------------------------------------------------------------------------
// Kernel 5 (qh-split + XCD swizzle): 512 blocks = 64 idx x 8 xcd.
// ---------------------------------------------------------------------------
__global__ __launch_bounds__(512)
void res_kernel(const float2* __restrict__ E, const float* __restrict__ AwT,
                const float2* __restrict__ peT,
                const float* __restrict__ encr, const float* __restrict__ enci,
                float2* __restrict__ Res) {
    int bid = blockIdx.x;
    int xcd = bid & 7;
    int idx = bid >> 3;                   // 0..63
    int bh = xcd * 8 + (idx & 7);         // b*NHH+h
    int mqh = idx >> 3;                   // 0..7
    int m  = mqh >> 1;
    int qh = mqh & 1;
    int h = bh & 7;
    int b = bh >> 3;
    int i = threadIdx.x & 255;
    int g = threadIdx.x >> 8;             // j-half 0/1

    __shared__ float2 sv[8][NN];          // 16 KB: this qh's 8 V rows
    __shared__ float2 spA[NN][9];         // 18 KB: g=1 partials (8 acc + PA)
    __shared__ float2 senc[8];

    const float2* V = E + ((size_t)(((2 * BB + b) * MM + m) * NHH + h) * QDD + qh * 8) * NN;
    for (int i2 = threadIdx.x; i2 < 8 * NN; i2 += 512) sv[i2 >> 8][i2 & 255] = V[i2];
    if (threadIdx.x < 8) {
        int eb = ((MM + m) * NHH + h) * QDD + qh * 8 + threadIdx.x;   // enc[1,...]
        senc[threadIdx.x] = make_float2(encr[eb], enci[eb]);
    }
    __syncthreads();

    float accr[8], acci[8];
#pragma unroll
    for (int q = 0; q < 8; ++q) { accr[q] = 0.f; acci[q] = 0.f; }
    float par = 0.f, pai = 0.f;

    const float*  awp = AwT + (size_t)((b * NHH + h) * NN) * NN + i;
    const float2* pep = peT + (size_t)(m * NN) * NN + i;
    int j0 = g * (NN / 2);
    for (int j = j0; j < j0 + NN / 2; ++j) {
        float aw  = awp[(size_t)j * NN];      // coalesced over i
        float2 p  = pep[(size_t)j * NN];      // coalesced over i
        par = fmaf(p.x, aw, par);
        pai = fmaf(p.y, aw, pai);
#pragma unroll
        for (int q = 0; q < 8; ++q) {
            float2 vv = sv[q][j];             // wave-uniform -> broadcast
            accr[q] = fmaf(vv.x, aw, accr[q]);
            acci[q] = fmaf(vv.y, aw, acci[q]);
        }
    }

    if (g == 1) {
#pragma unroll
        for (int q = 0; q < 8; ++q) spA[i][q] = make_float2(accr[q], acci[q]);
        spA[i][8] = make_float2(par, pai);
    }
    __syncthreads();
    if (g == 0) {
#pragma unroll
        for (int q = 0; q < 8; ++q) {
            float2 o = spA[i][q];
            accr[q] += o.x; acci[q] += o.y;
        }
        float2 o = spA[i][8];
        par += o.x; pai += o.y;

        float2* rp = Res + ((size_t)((b * MM + m) * KO + h * QDD + qh * 8)) * NN + i;
#pragma unroll
        for (int q = 0; q < 8; ++q) {
            float2 e1 = senc[q];
            float rr = accr[q] + e1.x * par - e1.y * pai;
            float ri = acci[q] + e1.x * pai + e1.y * par;
            rp[(size_t)q * NN] = make_float2(rr, ri);
        }
    }
}

// ---------------------------------------------------------------------------
// Kernel 6 (DTILE=8 + XCD swizzle): out[b,m,D,n] = sum_k w_out*res.
// ---------------------------------------------------------------------------
__global__ void out_kernel(const float2* __restrict__ Res,
                           const float* __restrict__ wor, const float* __restrict__ woi,
                           float* __restrict__ out) {
    int bid = blockIdx.x;
    int xcd = bid & 7;
    int idx = bid >> 3;                   // 0..63
    int bm = xcd * 4 + (idx & 3);         // b*MM+m, 0..31
    int dt = idx >> 2;                    // 0..15
    int n = threadIdx.x;
    int D0 = dt * DTILE;
    int m = bm & 3;

    __shared__ float2 sw[DTILE][KO];      // 8 KB
    for (int i2 = threadIdx.x; i2 < DTILE * KO; i2 += 256) {
        int d = i2 >> 7, k = i2 & 127;
        int wb = (m * DD + D0 + d) * KO + k;
        sw[d][k] = make_float2(wor[wb], woi[wb]);
    }
    __syncthreads();

    const float2* rp = Res + (size_t)(bm * KO) * NN + n;
    float ar[DTILE], ai[DTILE];
#pragma unroll
    for (int d = 0; d < DTILE; ++d) { ar[d] = 0.f; ai[d] = 0.f; }

    for (int k = 0; k < KO; ++k) {
        float2 r = rp[(size_t)k * NN];    // coalesced
#pragma unroll
        for (int d = 0; d < DTILE; ++d) {
            float2 w = sw[d][k];          // broadcast
            ar[d] = fmaf(w.x, r.x, fmaf(-w.y, r.y, ar[d]));
            ai[d] = fmaf(w.x, r.y, fmaf( w.y, r.x, ai[d]));
        }
    }
#pragma unroll
    for (int d = 0; d < DTILE; ++d) {
        size_t ob = (size_t)(bm * DD + D0 + d) * NN + n;
        out[ob] = ar[d];
        out[(size_t)BB * MM * DD * NN + ob] = ai[d];
    }
}

// ---------------------------------------------------------------------------
extern "C" void kernel_launch(void* const* d_in, const int* in_sizes, int n_in,
                              void* d_out, int out_size, void* d_ws, size_t ws_size,
                              hipStream_t stream) {
    (void)in_sizes; (void)n_in; (void)out_size; (void)ws_size;

    const float* x_re   = (const float*)d_in[0];
    const float* x_im   = (const float*)d_in[1];
    const float* emb_re = (const float*)d_in[2];
    const float* emb_im = (const float*)d_in[3];
    const float* enc_re = (const float*)d_in[4];
    const float* enc_im = (const float*)d_in[5];
    const float* out_re = (const float*)d_in[6];
    const float* out_im = (const float*)d_in[7];
    float* out = (float*)d_out;

    // Workspace layout (floats). Total ~155.7 MB.
    float* ws = (float*)d_ws;
    size_t off = 0;
    float2* peIJ = (float2*)(ws + off); off += (size_t)MM * NN * NN * 2;          // 524288
    float2* peT  = (float2*)(ws + off); off += (size_t)MM * NN * NN * 2;          // 524288
    float2* E    = (float2*)(ws + off); off += (size_t)3 * BB * MM * NHH * QDD * NN * 2; // 25165824
    float2* QE   = (float2*)(ws + off); off += (size_t)BB * MM * NHH * NN * 2;    // 131072
    float2* A    = (float2*)(ws + off); off += (size_t)BB * NHH * NN * NN * 2;    // 8388608
    float*  AwT  = (float*)(ws + off);  off += (size_t)BB * NHH * NN * NN;        // 4194304
    float2* Res  = A;  // alias: A is dead after softmax; Res needs 2097152 floats

    pe_kernel<<<MM * NN, 256, 0, stream>>>(peIJ, peT);
    e_kernel<<<3 * BB * MM * NHH, 256, 0, stream>>>(x_re, x_im, emb_re, emb_im, E);
    qe_kernel<<<BB * MM * NHH, 256, 0, stream>>>(E, enc_re, enc_im, QE);
    a_kernel<<<BB * NHH * ATILE, 256, 0, stream>>>(E, QE, peIJ, A);
    softmax_kernel<<<BB * NHH * NN, 256, 0, stream>>>(A, AwT);
    res_kernel<<<BB * MM * NHH * 2, 512, 0, stream>>>(E, AwT, peT, enc_re, enc_im, Res);
    out_kernel<<<BB * MM * (DD / DTILE), 256, 0, stream>>>(Res, out_re, out_im, out);
}

// Round 20
// 174.188 us; speedup vs baseline: 1.0622x; 1.0391x over previous
//
#include <hip/hip_runtime.h>
#include <math.h>

// Problem constants (from reference)
#define BB   8      // batch
#define MM   4      // MAXM
#define DD   128    // DIM
#define NHH  8      // heads
#define QDD  16     // head dim
#define NN   256    // H*W
#define KO   128    // NH*QD
#define DTILE 8     // D-rows per out_kernel block

typedef float v2f __attribute__((ext_vector_type(2)));
#define PKFMA(a, b, c) __builtin_elementwise_fma((a), (b), (c))

// ---------------------------------------------------------------------------
// Kernel 0 (trig-free): pe[m,i,j] = exp(i*m*theta) = ((dx+i*dy)/r)^m.
// ---------------------------------------------------------------------------
__global__ void pe_kernel(float2* __restrict__ peIJ, float2* __restrict__ peT) {
    int bid = blockIdx.x;           // m*N + i
    int m = bid >> 8;
    int i = bid & 255;
    int j = threadIdx.x;
    float dy = (float)((j >> 4) - (i >> 4));
    float dx = (float)((j & 15) - (i & 15));
    float r2 = dx * dx + dy * dy;
    float c1 = 1.f, s1 = 0.f;
    if (r2 > 0.f) {
        float rinv = rsqrtf(r2);
        c1 = dx * rinv; s1 = dy * rinv;
    }
    float c = 1.f, s = 0.f;
    for (int k = 0; k < m; ++k) {   // m is block-uniform (0..3)
        float nc = c * c1 - s * s1;
        s = c * s1 + s * c1;
        c = nc;
    }
    peIJ[(m * NN + i) * NN + j] = make_float2(c, s);
    peT[(m * NN + j) * NN + i] = make_float2(c, s);
}

// ---------------------------------------------------------------------------
// Kernel 1 (v10): E[t,b,m,h,q,n] = sum_D emb*x, cooperative x staging.
// ---------------------------------------------------------------------------
__global__ __launch_bounds__(256, 3)
void e_kernel(const float* __restrict__ xr, const float* __restrict__ xi,
              const float* __restrict__ er, const float* __restrict__ ei,
              float2* __restrict__ E) {
    int bid = blockIdx.x;
    int xcd = bid & 7;
    int idx = bid >> 3;                   // 0..95
    int pair = xcd * 4 + (idx & 3);       // b*MM+m, 0..31
    int th  = idx >> 2;                   // 0..23 = t*NHH+h
    int t = th >> 3;
    int h = th & 7;
    int b = pair >> 2;
    int m = pair & 3;
    int tid = threadIdx.x;
    int wav = tid >> 6;                   // 0..3 (wave id = q-quad)
    int lane = tid & 63;                  // n = 4*lane .. 4*lane+3

    __shared__ float2 semb[QDD * DD];     // 16 KB, [q*128+D] (linear)
    __shared__ float4 sxr4[8 * 64];       // 8 KB: x_re chunk (8 D-rows)
    __shared__ float4 sxi4[8 * 64];       // 8 KB: x_im chunk
    int base = (((t * MM + m) * NHH + h) * QDD) * DD;
    for (int i2 = tid; i2 < QDD * DD; i2 += 256)
        semb[i2] = make_float2(er[base + i2], ei[base + i2]);

    v2f accr[4][2], acci[4][2];           // [qq][n-half]
#pragma unroll
    for (int q = 0; q < 4; ++q)
#pragma unroll
        for (int hh = 0; hh < 2; ++hh) { accr[q][hh] = (v2f)(0.f); acci[q][hh] = (v2f)(0.f); }

    const float4* xr4 = (const float4*)(xr + (size_t)((b * MM + m) * DD) * NN);
    const float4* xi4 = (const float4*)(xi + (size_t)((b * MM + m) * DD) * NN);
    const float2* sq = semb + wav * 4 * DD;   // this wave's 4 q rows

    for (int Dc = 0; Dc < DD; Dc += 8) {
        __syncthreads();                  // protect previous chunk (also covers semb)
        const float4* srcR = xr4 + Dc * 64;
        const float4* srcI = xi4 + Dc * 64;
        sxr4[tid]       = srcR[tid];
        sxr4[tid + 256] = srcR[tid + 256];
        sxi4[tid]       = srcI[tid];
        sxi4[tid + 256] = srcI[tid + 256];
        __syncthreads();

#pragma unroll
        for (int d = 0; d < 8; ++d) {
            float4 vr = sxr4[d * 64 + lane];   // b128, conflict-free
            float4 vi = sxi4[d * 64 + lane];
            v2f vr0 = {vr.x, vr.y}, vr1 = {vr.z, vr.w};
            v2f vi0 = {vi.x, vi.y}, vi1 = {vi.z, vi.w};
#pragma unroll
            for (int qq = 0; qq < 4; ++qq) {
                float2 e = sq[qq * DD + Dc + d];  // wave-uniform broadcast
                v2f ex  = {e.x, e.x};
                v2f ey  = {e.y, e.y};
                v2f ney = -ey;
                accr[qq][0] = PKFMA(ex, vr0, PKFMA(ney, vi0, accr[qq][0]));
                acci[qq][0] = PKFMA(ex, vi0, PKFMA(ey,  vr0, acci[qq][0]));
                accr[qq][1] = PKFMA(ex, vr1, PKFMA(ney, vi1, accr[qq][1]));
                acci[qq][1] = PKFMA(ex, vi1, PKFMA(ey,  vr1, acci[qq][1]));
            }
        }
    }

    size_t ebase = (size_t)((((t * BB + b) * MM + m) * NHH + h) * QDD + wav * 4) * NN
                 + 4 * lane;
#pragma unroll
    for (int qq = 0; qq < 4; ++qq) {
        float4* E4 = (float4*)(E + ebase + (size_t)qq * NN);
        E4[0] = make_float4(accr[qq][0].x, acci[qq][0].x, accr[qq][0].y, acci[qq][0].y);
        E4[1] = make_float4(accr[qq][1].x, acci[qq][1].x, accr[qq][1].y, acci[qq][1].y);
    }
}

// ---------------------------------------------------------------------------
// Kernel 2: QE[b,m,h,i] = sum_q conj(E0[b,m,h,q,i]) * enc0[m,h,q]
// ---------------------------------------------------------------------------
__global__ void qe_kernel(const float2* __restrict__ E,
                          const float* __restrict__ encr, const float* __restrict__ enci,
                          float2* __restrict__ QE) {
    int bid = blockIdx.x;                 // (b*MM+m)*NHH + h
    int i = threadIdx.x;
    const float2* e0 = E + (size_t)(bid) * QDD * NN;   // t=0 plane
    int h = bid & 7;
    int bm = bid >> 3;
    int m = bm & 3;
    int encbase = (m * NHH + h) * QDD;    // enc[0,m,h,0,q,0]
    float ar = 0.f, ai = 0.f;
#pragma unroll
    for (int q = 0; q < QDD; ++q) {
        float2 e = e0[q * NN + i];
        float cr = encr[encbase + q], ci = enci[encbase + q];
        // conj(e) * enc
        ar = fmaf(e.x, cr, fmaf( e.y, ci, ar));
        ai = fmaf(e.x, ci, fmaf(-e.y, cr, ai));
    }
    QE[(size_t)bid * NN + i] = make_float2(ar, ai);
}

// ---------------------------------------------------------------------------
// Kernel 3 (v4: 512 thr, 2 itiles/block): A[b,h,i,j].
// Two 256-thread j-groups share ONE sk staging (half the staging per output);
// 8 waves/block x 4 blocks/CU = 32 waves/CU (100% occupancy cap).
// ---------------------------------------------------------------------------
__global__ __launch_bounds__(512)
void a_kernel(const float2* __restrict__ E, const float2* __restrict__ QE,
              const float2* __restrict__ peIJ, float2* __restrict__ A) {
    int bid = blockIdx.x;                 // 512 blocks = 8 xcd x 64 idx
    int xcd = bid & 7;
    int idx = bid >> 3;                   // 0..63
    int bh = xcd * 8 + (idx & 7);         // b*NHH+h, 0..63
    int ipair = idx >> 3;                 // 0..7 (pair of itiles)
    int h = bh & 7;
    int b = bh >> 3;
    int tid = threadIdx.x;
    int sub = tid >> 8;                   // 0/1: which itile
    int j = tid & 255;
    int i0b = ipair * 32;                 // block's 32 i-rows
    int i0 = i0b + sub * 16;              // this group's 16 rows

    __shared__ float2 sk[QDD][NN];        // 32 KB
    __shared__ float seX[QDD][32];        // 2 KB (SoA over 32 rows)
    __shared__ float seY[QDD][32];        // 2 KB
    __shared__ float sqeX[32];
    __shared__ float sqeY[32];

    v2f ar2[8], ai2[8];
#pragma unroll
    for (int rp = 0; rp < 8; ++rp) { ar2[rp] = (v2f)(0.f); ai2[rp] = (v2f)(0.f); }

    for (int m = 0; m < MM; ++m) {
        const float2* kk = E + (size_t)((((BB + b) * MM + m) * NHH + h) * QDD) * NN; // t=1
        const float2* e0 = E + (size_t)(((b * MM + m) * NHH + h) * QDD) * NN;        // t=0
        __syncthreads();
        for (int i2 = tid; i2 < QDD * NN; i2 += 512)
            sk[i2 >> 8][i2 & 255] = kk[i2];
        {
            int q = tid & 15;
            int r = tid >> 4;             // 0..31
            float2 e = e0[q * NN + i0b + r];
            seX[q][r] = e.x;
            seY[q][r] = e.y;
        }
        if (tid < 32) {
            float2 qe = QE[(size_t)((b * MM + m) * NHH + h) * NN + i0b + tid];
            sqeX[tid] = qe.x;
            sqeY[tid] = qe.y;
        }
        __syncthreads();

        // this thread's K column into registers
        float2 kreg[QDD];
#pragma unroll
        for (int q = 0; q < QDD; ++q) kreg[q] = sk[q][j];

#pragma unroll
        for (int q = 0; q < QDD; ++q) {
            v2f kx  = {kreg[q].x, kreg[q].x};
            v2f ky  = {kreg[q].y, kreg[q].y};
            v2f nkx = -kx;
#pragma unroll
            for (int rp = 0; rp < 8; ++rp) {
                v2f ex = *(const v2f*)&seX[q][sub * 16 + 2 * rp];  // group-uniform
                v2f ey = *(const v2f*)&seY[q][sub * 16 + 2 * rp];
                // ar[r] += e.x*k.x + e.y*k.y ; ai[r] += e.x*k.y - e.y*k.x
                ar2[rp] = PKFMA(ex, kx, PKFMA(ey, ky,  ar2[rp]));
                ai2[rp] = PKFMA(ex, ky, PKFMA(ey, nkx, ai2[rp]));
            }
        }

        // pe term: ar[r] += qe.x*p.x - qe.y*p.y ; ai[r] += qe.x*p.y + qe.y*p.x
#pragma unroll
        for (int rp = 0; rp < 8; ++rp) {
            float2 p0 = peIJ[(size_t)(m * NN + i0 + 2 * rp) * NN + j];     // coalesced
            float2 p1 = peIJ[(size_t)(m * NN + i0 + 2 * rp + 1) * NN + j];
            v2f px = {p0.x, p1.x}, py = {p0.y, p1.y};
            v2f qx = *(const v2f*)&sqeX[sub * 16 + 2 * rp];
            v2f qy = *(const v2f*)&sqeY[sub * 16 + 2 * rp];
            v2f nqy = -qy;
            ar2[rp] = PKFMA(px, qx, PKFMA(py, nqy, ar2[rp]));
            ai2[rp] = PKFMA(py, qx, PKFMA(px, qy,  ai2[rp]));
        }
    }
#pragma unroll
    for (int rp = 0; rp < 8; ++rp) {
        A[(size_t)(bh * NN + i0 + 2 * rp) * NN + j]     = make_float2(ar2[rp].x, ai2[rp].x);
        A[(size_t)(bh * NN + i0 + 2 * rp + 1) * NN + j] = make_float2(ar2[rp].y, ai2[rp].y);
    }
}

// ---------------------------------------------------------------------------
// Kernel 4: row softmax of |A|/4 over j; writes TRANSPOSED Aw:
//   AwT[(bh*N + j)*N + i]
// ---------------------------------------------------------------------------
__global__ void softmax_kernel(const float2* __restrict__ A, float* __restrict__ AwT) {
    int row = blockIdx.x;                 // (b*NHH+h)*NN + i
    int j = threadIdx.x;
    float2 a = A[(size_t)row * NN + j];
    float v = sqrtf(fmaf(a.x, a.x, a.y * a.y)) * 0.25f;

    __shared__ float smax[4];
    __shared__ float ssum[4];
    int lane = threadIdx.x & 63;
    int wid  = threadIdx.x >> 6;

    float mv = v;
#pragma unroll
    for (int off = 32; off > 0; off >>= 1) mv = fmaxf(mv, __shfl_xor(mv, off));
    if (lane == 0) smax[wid] = mv;
    __syncthreads();
    float mx = fmaxf(fmaxf(smax[0], smax[1]), fmaxf(smax[2], smax[3]));

    float e = expf(v - mx);
    float sv = e;
#pragma unroll
    for (int off = 32; off > 0; off >>= 1) sv += __shfl_xor(sv, off);
    if (lane == 0) ssum[wid] = sv;
    __syncthreads();
    float sum = ssum[0] + ssum[1] + ssum[2] + ssum[3];

    float aw = e / sum;
    int bh = row >> 8;
    int i  = row & 255;
    AwT[(size_t)(bh * NN + j) * NN + i] = aw;
}

// ---------------------------------------------------------------------------
// Kernel 5 (qh-split + XCD swizzle): 512 blocks = 64 idx x 8 xcd.
// ---------------------------------------------------------------------------
__global__ __launch_bounds__(512)
void res_kernel(const float2* __restrict__ E, const float* __restrict__ AwT,
                const float2* __restrict__ peT,
                const float* __restrict__ encr, const float* __restrict__ enci,
                float2* __restrict__ Res) {
    int bid = blockIdx.x;
    int xcd = bid & 7;
    int idx = bid >> 3;                   // 0..63
    int bh = xcd * 8 + (idx & 7);         // b*NHH+h
    int mqh = idx >> 3;                   // 0..7
    int m  = mqh >> 1;
    int qh = mqh & 1;
    int h = bh & 7;
    int b = bh >> 3;
    int i = threadIdx.x & 255;
    int g = threadIdx.x >> 8;             // j-half 0/1

    __shared__ float2 sv[8][NN];          // 16 KB: this qh's 8 V rows
    __shared__ float2 spA[NN][9];         // 18 KB: g=1 partials (8 acc + PA)
    __shared__ float2 senc[8];

    const float2* V = E + ((size_t)(((2 * BB + b) * MM + m) * NHH + h) * QDD + qh * 8) * NN;
    for (int i2 = threadIdx.x; i2 < 8 * NN; i2 += 512) sv[i2 >> 8][i2 & 255] = V[i2];
    if (threadIdx.x < 8) {
        int eb = ((MM + m) * NHH + h) * QDD + qh * 8 + threadIdx.x;   // enc[1,...]
        senc[threadIdx.x] = make_float2(encr[eb], enci[eb]);
    }
    __syncthreads();

    float accr[8], acci[8];
#pragma unroll
    for (int q = 0; q < 8; ++q) { accr[q] = 0.f; acci[q] = 0.f; }
    float par = 0.f, pai = 0.f;

    const float*  awp = AwT + (size_t)((b * NHH + h) * NN) * NN + i;
    const float2* pep = peT + (size_t)(m * NN) * NN + i;
    int j0 = g * (NN / 2);
    for (int j = j0; j < j0 + NN / 2; ++j) {
        float aw  = awp[(size_t)j * NN];      // coalesced over i
        float2 p  = pep[(size_t)j * NN];      // coalesced over i
        par = fmaf(p.x, aw, par);
        pai = fmaf(p.y, aw, pai);
#pragma unroll
        for (int q = 0; q < 8; ++q) {
            float2 vv = sv[q][j];             // wave-uniform -> broadcast
            accr[q] = fmaf(vv.x, aw, accr[q]);
            acci[q] = fmaf(vv.y, aw, acci[q]);
        }
    }

    if (g == 1) {
#pragma unroll
        for (int q = 0; q < 8; ++q) spA[i][q] = make_float2(accr[q], acci[q]);
        spA[i][8] = make_float2(par, pai);
    }
    __syncthreads();
    if (g == 0) {
#pragma unroll
        for (int q = 0; q < 8; ++q) {
            float2 o = spA[i][q];
            accr[q] += o.x; acci[q] += o.y;
        }
        float2 o = spA[i][8];
        par += o.x; pai += o.y;

        float2* rp = Res + ((size_t)((b * MM + m) * KO + h * QDD + qh * 8)) * NN + i;
#pragma unroll
        for (int q = 0; q < 8; ++q) {
            float2 e1 = senc[q];
            float rr = accr[q] + e1.x * par - e1.y * pai;
            float ri = acci[q] + e1.x * pai + e1.y * par;
            rp[(size_t)q * NN] = make_float2(rr, ri);
        }
    }
}

// ---------------------------------------------------------------------------
// Kernel 6 (DTILE=8 + XCD swizzle): out[b,m,D,n] = sum_k w_out*res.
// ---------------------------------------------------------------------------
__global__ void out_kernel(const float2* __restrict__ Res,
                           const float* __restrict__ wor, const float* __restrict__ woi,
                           float* __restrict__ out) {
    int bid = blockIdx.x;
    int xcd = bid & 7;
    int idx = bid >> 3;                   // 0..63
    int bm = xcd * 4 + (idx & 3);         // b*MM+m, 0..31
    int dt = idx >> 2;                    // 0..15
    int n = threadIdx.x;
    int D0 = dt * DTILE;
    int m = bm & 3;

    __shared__ float2 sw[DTILE][KO];      // 8 KB
    for (int i2 = threadIdx.x; i2 < DTILE * KO; i2 += 256) {
        int d = i2 >> 7, k = i2 & 127;
        int wb = (m * DD + D0 + d) * KO + k;
        sw[d][k] = make_float2(wor[wb], woi[wb]);
    }
    __syncthreads();

    const float2* rp = Res + (size_t)(bm * KO) * NN + n;
    float ar[DTILE], ai[DTILE];
#pragma unroll
    for (int d = 0; d < DTILE; ++d) { ar[d] = 0.f; ai[d] = 0.f; }

    for (int k = 0; k < KO; ++k) {
        float2 r = rp[(size_t)k * NN];    // coalesced
#pragma unroll
        for (int d = 0; d < DTILE; ++d) {
            float2 w = sw[d][k];          // broadcast
            ar[d] = fmaf(w.x, r.x, fmaf(-w.y, r.y, ar[d]));
            ai[d] = fmaf(w.x, r.y, fmaf( w.y, r.x, ai[d]));
        }
    }
#pragma unroll
    for (int d = 0; d < DTILE; ++d) {
        size_t ob = (size_t)(bm * DD + D0 + d) * NN + n;
        out[ob] = ar[d];
        out[(size_t)BB * MM * DD * NN + ob] = ai[d];
    }
}

// ---------------------------------------------------------------------------
extern "C" void kernel_launch(void* const* d_in, const int* in_sizes, int n_in,
                              void* d_out, int out_size, void* d_ws, size_t ws_size,
                              hipStream_t stream) {
    (void)in_sizes; (void)n_in; (void)out_size; (void)ws_size;

    const float* x_re   = (const float*)d_in[0];
    const float* x_im   = (const float*)d_in[1];
    const float* emb_re = (const float*)d_in[2];
    const float* emb_im = (const float*)d_in[3];
    const float* enc_re = (const float*)d_in[4];
    const float* enc_im = (const float*)d_in[5];
    const float* out_re = (const float*)d_in[6];
    const float* out_im = (const float*)d_in[7];
    float* out = (float*)d_out;

    // Workspace layout (floats). Total ~155.7 MB.
    float* ws = (float*)d_ws;
    size_t off = 0;
    float2* peIJ = (float2*)(ws + off); off += (size_t)MM * NN * NN * 2;          // 524288
    float2* peT  = (float2*)(ws + off); off += (size_t)MM * NN * NN * 2;          // 524288
    float2* E    = (float2*)(ws + off); off += (size_t)3 * BB * MM * NHH * QDD * NN * 2; // 25165824
    float2* QE   = (float2*)(ws + off); off += (size_t)BB * MM * NHH * NN * 2;    // 131072
    float2* A    = (float2*)(ws + off); off += (size_t)BB * NHH * NN * NN * 2;    // 8388608
    float*  AwT  = (float*)(ws + off);  off += (size_t)BB * NHH * NN * NN;        // 4194304
    float2* Res  = A;  // alias: A is dead after softmax; Res needs 2097152 floats

    pe_kernel<<<MM * NN, 256, 0, stream>>>(peIJ, peT);
    e_kernel<<<3 * BB * MM * NHH, 256, 0, stream>>>(x_re, x_im, emb_re, emb_im, E);
    qe_kernel<<<BB * MM * NHH, 256, 0, stream>>>(E, enc_re, enc_im, QE);
    a_kernel<<<BB * NHH * 8, 512, 0, stream>>>(E, QE, peIJ, A);
    softmax_kernel<<<BB * NHH * NN, 256, 0, stream>>>(A, AwT);
    res_kernel<<<BB * MM * NHH * 2, 512, 0, stream>>>(E, AwT, peT, enc_re, enc_im, Res);
    out_kernel<<<BB * MM * (DD / DTILE), 256, 0, stream>>>(Res, out_re, out_im, out);
}